// Round 6
// baseline (99.441 us; speedup 1.0000x reference)
//
#include <hip/hip_runtime.h>
#include <math.h>

#define FW 1.0f
#define BW 1.0f
#define NW 0.1f
#define EPSV 1e-6f

#define BT  256   // threads per block
#define MPT 8     // A-points per thread (2048 per block)
#define JCH 128   // B-points staged per chunk

// Rotation from 6d, columns b1,b2,b3 (R = stack([b1,b2,b3], axis=1)).
#define COMPUTE_R(r6)                                                         \
    float a1x = (r6)[0], a1y = (r6)[1], a1z = (r6)[2];                        \
    float a2x = (r6)[3], a2y = (r6)[4], a2z = (r6)[5];                        \
    float n1 = sqrtf(a1x*a1x + a1y*a1y + a1z*a1z);                            \
    float b1x = a1x/n1, b1y = a1y/n1, b1z = a1z/n1;                           \
    float dp = b1x*a2x + b1y*a2y + b1z*a2z;                                   \
    float u2x = a2x - dp*b1x, u2y = a2y - dp*b1y, u2z = a2z - dp*b1z;         \
    float n2 = sqrtf(u2x*u2x + u2y*u2y + u2z*u2z);                            \
    float b2x = u2x/n2, b2y = u2y/n2, b2z = u2z/n2;                           \
    float b3x = b1y*b2z - b1z*b2y;                                            \
    float b3y = b1z*b2x - b1x*b2z;                                            \
    float b3z = b1x*b2y - b1y*b2x;

// ---------------------------------------------------------------------------
// Transform: y==0: src4[i]=(R*(scale*sp)+t, |.|^2), srcn4[i]=R*sn,
//                  min_s[i]=~0  (init folded in — no separate memset launch)
//            y==1: tgt4[j]=(tp, |tp|^2), min_t[j]=~0
// ---------------------------------------------------------------------------
__global__ __launch_bounds__(BT) void transform_kernel(
    const float* __restrict__ sp, const float* __restrict__ tp,
    const float* __restrict__ sn,
    const float* __restrict__ trans, const float* __restrict__ r6,
    const float* __restrict__ scl,
    float4* __restrict__ src4, float4* __restrict__ tgt4,
    float4* __restrict__ srcn4,
    unsigned long long* __restrict__ min_s,
    unsigned long long* __restrict__ min_t,
    float* __restrict__ out, int N, int M)
{
    int i = blockIdx.x * BT + threadIdx.x;

    if (blockIdx.y == 1) {
        if (i < M) {
            float x = tp[3*i], y = tp[3*i+1], z = tp[3*i+2];
            tgt4[i] = make_float4(x, y, z, x*x + y*y + z*z);
            min_t[i] = ~0ull;
        }
        return;
    }

    if (i == 0) out[0] = 0.f;     // base for reduce's atomicAdd
    if (i >= N) return;
    min_s[i] = ~0ull;

    COMPUTE_R(r6)

    float qx = sp[3*i]   * scl[0];
    float qy = sp[3*i+1] * scl[1];
    float qz = sp[3*i+2] * scl[2];
    float sx = b1x*qx + b2x*qy + b3x*qz + trans[0];
    float sy = b1y*qx + b2y*qy + b3y*qz + trans[1];
    float sz = b1z*qx + b2z*qy + b3z*qz + trans[2];
    src4[i] = make_float4(sx, sy, sz, sx*sx + sy*sy + sz*sz);

    float nx = sn[3*i], ny = sn[3*i+1], nz = sn[3*i+2];
    srcn4[i] = make_float4(b1x*nx + b2x*ny + b3x*nz,
                           b1y*nx + b2y*ny + b3y*nz,
                           b1z*nx + b2z*ny + b3z*nz, 0.f);
}

// ---------------------------------------------------------------------------
// Min kernel: block = 2048 A x 128 B(LDS). Inner loop is 4 VALU/pair:
// 3 fma (e = t2 - 2*dot, monotone per row) + v_min_f32. NO index tracking —
// only the chunk id is recorded; argmin-within-chunk is recovered by the
// reduce kernel's 128-point rescan. Packed (d|chunkId) u64 atomicMin:
// equal d -> smaller chunk -> first-occurrence argmin preserved.
// ---------------------------------------------------------------------------
__global__ __launch_bounds__(BT) void min_kernel(
    const float4* __restrict__ src4, const float4* __restrict__ tgt4,
    unsigned long long* __restrict__ min_s,
    unsigned long long* __restrict__ min_t, int N, int M)
{
    const float4* A; const float4* B; unsigned long long* outm; int nA, nB;
    if (blockIdx.z == 0) { A = src4; B = tgt4; outm = min_s; nA = N; nB = M; }
    else                 { A = tgt4; B = src4; outm = min_t; nA = M; nB = N; }

    const int tid   = threadIdx.x;
    const int aBase = blockIdx.x * (BT * MPT);
    const int jBase = blockIdx.y * JCH;
    if (aBase >= nA || jBase >= nB) return;   // block-uniform

    __shared__ float4 bs[JCH];

    float cx[MPT], cy[MPT], cz[MPT], s2[MPT], best[MPT];
    #pragma unroll
    for (int p = 0; p < MPT; p++) {
        int ia = aBase + p*BT + tid; if (ia >= nA) ia = 0;
        float4 a = A[ia];
        cx[p] = -2.f*a.x; cy[p] = -2.f*a.y; cz[p] = -2.f*a.z;
        s2[p] = a.w;
        best[p] = 3.4e38f;
    }
    if (tid < JCH) {
        int jb = jBase + tid;
        bs[tid] = B[jb < nB ? jb : nB - 1];
    }
    __syncthreads();

    int jLim = nB - jBase; if (jLim > JCH) jLim = JCH;
    #pragma unroll 2
    for (int j = 0; j < jLim; j++) {
        float4 b = bs[j];                    // wave-uniform -> LDS broadcast
        #pragma unroll
        for (int p = 0; p < MPT; p++) {
            float e = fmaf(cz[p], b.z, b.w);
            e = fmaf(cy[p], b.y, e);
            e = fmaf(cx[p], b.x, e);
            best[p] = fminf(best[p], e);
        }
    }

    #pragma unroll
    for (int p = 0; p < MPT; p++) {
        int ia = aBase + p*BT + tid;
        if (ia < nA) {
            float d = fmaxf(best[p] + s2[p], 0.f);
            unsigned long long pk =
                ((unsigned long long)__float_as_uint(d) << 32) |
                (unsigned int)blockIdx.y;
            atomicMin(&outm[ia], pk);
        }
    }
}

// ---------------------------------------------------------------------------
// Reduce: per point, rescan the winning 128-point chunk (same fma chain on
// the same stored float4s -> same e values) to recover exact min + first
// argmin; then normal cosine term; block reduce; one atomicAdd per block.
// ---------------------------------------------------------------------------
__global__ __launch_bounds__(BT) void reduce_kernel(
    const unsigned long long* __restrict__ min_s,
    const unsigned long long* __restrict__ min_t,
    const float4* __restrict__ src4, const float4* __restrict__ tgt4,
    const float4* __restrict__ srcn4, const float* __restrict__ tn,
    float* __restrict__ out, int N, int M)
{
    int gid = blockIdx.x * BT + threadIdx.x;
    float contrib = 0.f;

    if (gid < N + M) {
        const int dir = (gid < N) ? 0 : 1;
        const int i   = dir ? (gid - N) : gid;
        const float4* Ap = dir ? tgt4 : src4;
        const float4* Bp = dir ? src4 : tgt4;
        const int nB  = dir ? N : M;
        unsigned long long pk = dir ? min_t[i] : min_s[i];

        const int jBase = (int)(unsigned int)(pk & 0xffffffffull) * JCH;
        int jLim = nB - jBase; if (jLim > JCH) jLim = JCH;

        float4 a = Ap[i];
        float cx = -2.f*a.x, cy = -2.f*a.y, cz = -2.f*a.z;

        float bestE = 3.4e38f; int bestJ = 0;
        const float4* bp = Bp + jBase;
        #pragma unroll 4
        for (int j = 0; j < jLim; j++) {
            float4 b = bp[j];
            float e = fmaf(cz, b.z, b.w);
            e = fmaf(cy, b.y, e);
            e = fmaf(cx, b.x, e);
            bool c = e < bestE;              // strict: first occurrence wins
            bestE = c ? e : bestE;
            bestJ = c ? j : bestJ;
        }
        float d = fmaxf(bestE + a.w, 0.f);
        int idx = jBase + bestJ;

        if (dir == 0) {
            float4 nv = srcn4[i];
            float tx = tn[3*idx], ty = tn[3*idx+1], tz = tn[3*idx+2];
            float na = fmaxf(sqrtf(nv.x*nv.x + nv.y*nv.y + nv.z*nv.z), EPSV);
            float nb = fmaxf(sqrtf(tx*tx + ty*ty + tz*tz), EPSV);
            float cs = (nv.x*tx + nv.y*ty + nv.z*tz) / (na * nb);
            contrib = (FW * d + NW * (1.f - fabsf(cs))) * (1.f / N);
        } else {
            float tx = tn[3*i], ty = tn[3*i+1], tz = tn[3*i+2];
            float4 nv = srcn4[idx];
            float na = fmaxf(sqrtf(tx*tx + ty*ty + tz*tz), EPSV);
            float nb = fmaxf(sqrtf(nv.x*nv.x + nv.y*nv.y + nv.z*nv.z), EPSV);
            float cs = (tx*nv.x + ty*nv.y + tz*nv.z) / (na * nb);
            contrib = (BW * d + NW * (1.f - fabsf(cs))) * (1.f / M);
        }
    }

    #pragma unroll
    for (int o = 32; o > 0; o >>= 1)
        contrib += __shfl_down(contrib, o, 64);

    __shared__ float wsum[BT/64];
    if ((threadIdx.x & 63) == 0) wsum[threadIdx.x >> 6] = contrib;
    __syncthreads();
    if (threadIdx.x == 0) {
        float s = 0.f;
        #pragma unroll
        for (int w = 0; w < BT/64; w++) s += wsum[w];
        atomicAdd(out, s);
    }
}

extern "C" void kernel_launch(void* const* d_in, const int* in_sizes, int n_in,
                              void* d_out, int out_size, void* d_ws, size_t ws_size,
                              hipStream_t stream) {
    const float* sp    = (const float*)d_in[0];
    const float* tp    = (const float*)d_in[1];
    const float* sn    = (const float*)d_in[2];
    const float* tn    = (const float*)d_in[3];
    const float* trans = (const float*)d_in[4];
    const float* r6    = (const float*)d_in[5];
    const float* scl   = (const float*)d_in[6];
    float* out = (float*)d_out;

    const int N = in_sizes[0] / 3;
    const int M = in_sizes[1] / 3;

    char* ws = (char*)d_ws;
    float4* src4  = (float4*)(ws);
    float4* tgt4  = (float4*)(ws + (size_t)16*N);
    float4* srcn4 = (float4*)(ws + (size_t)16*N + (size_t)16*M);
    unsigned long long* min_s =
        (unsigned long long*)(ws + (size_t)32*N + (size_t)16*M);
    unsigned long long* min_t = min_s + N;

    int nmax = N > M ? N : M;
    dim3 tgrid((nmax + BT - 1) / BT, 2);
    transform_kernel<<<tgrid, BT, 0, stream>>>(sp, tp, sn, trans, r6, scl,
                                               src4, tgt4, srcn4,
                                               min_s, min_t, out, N, M);

    dim3 mgrid((nmax + BT*MPT - 1) / (BT*MPT), (nmax + JCH - 1) / JCH, 2);
    min_kernel<<<mgrid, BT, 0, stream>>>(src4, tgt4, min_s, min_t, N, M);

    int rblocks = (N + M + BT - 1) / BT;
    reduce_kernel<<<rblocks, BT, 0, stream>>>(min_s, min_t, src4, tgt4,
                                              srcn4, tn, out, N, M);
}

// Round 7
// 89.580 us; speedup vs baseline: 1.1101x; 1.1101x over previous
//
#include <hip/hip_runtime.h>
#include <math.h>

#define FW 1.0f
#define BW 1.0f
#define NW 0.1f
#define EPSV 1e-6f

#define BT  256   // threads per block
#define MPT 8     // A-points per thread (2048 per block)
#define JCH 128   // B-points staged per chunk; j fits 8 mantissa bits

// Rotation from 6d, columns b1,b2,b3 (R = stack([b1,b2,b3], axis=1)).
#define COMPUTE_R(r6)                                                         \
    float a1x = (r6)[0], a1y = (r6)[1], a1z = (r6)[2];                        \
    float a2x = (r6)[3], a2y = (r6)[4], a2z = (r6)[5];                        \
    float n1 = sqrtf(a1x*a1x + a1y*a1y + a1z*a1z);                            \
    float b1x = a1x/n1, b1y = a1y/n1, b1z = a1z/n1;                           \
    float dp = b1x*a2x + b1y*a2y + b1z*a2z;                                   \
    float u2x = a2x - dp*b1x, u2y = a2y - dp*b1y, u2z = a2z - dp*b1z;         \
    float n2 = sqrtf(u2x*u2x + u2y*u2y + u2z*u2z);                            \
    float b2x = u2x/n2, b2y = u2y/n2, b2z = u2z/n2;                           \
    float b3x = b1y*b2z - b1z*b2y;                                            \
    float b3y = b1z*b2x - b1x*b2z;                                            \
    float b3z = b1x*b2y - b1y*b2x;

// ---------------------------------------------------------------------------
// Transform: y==0: src4[i]=(R*(scale*sp)+t, |.|^2), srcn4[i]=R*sn,
//                  min_s[i]=~0  (init folded in — no separate memset launch)
//            y==1: tgt4[j]=(tp, |tp|^2), min_t[j]=~0
// ---------------------------------------------------------------------------
__global__ __launch_bounds__(BT) void transform_kernel(
    const float* __restrict__ sp, const float* __restrict__ tp,
    const float* __restrict__ sn,
    const float* __restrict__ trans, const float* __restrict__ r6,
    const float* __restrict__ scl,
    float4* __restrict__ src4, float4* __restrict__ tgt4,
    float4* __restrict__ srcn4,
    unsigned long long* __restrict__ min_s,
    unsigned long long* __restrict__ min_t,
    float* __restrict__ out, int N, int M)
{
    int i = blockIdx.x * BT + threadIdx.x;

    if (blockIdx.y == 1) {
        if (i < M) {
            float x = tp[3*i], y = tp[3*i+1], z = tp[3*i+2];
            tgt4[i] = make_float4(x, y, z, x*x + y*y + z*z);
            min_t[i] = ~0ull;
        }
        return;
    }

    if (i == 0) out[0] = 0.f;     // base for reduce's atomicAdd
    if (i >= N) return;
    min_s[i] = ~0ull;

    COMPUTE_R(r6)

    float qx = sp[3*i]   * scl[0];
    float qy = sp[3*i+1] * scl[1];
    float qz = sp[3*i+2] * scl[2];
    float sx = b1x*qx + b2x*qy + b3x*qz + trans[0];
    float sy = b1y*qx + b2y*qy + b3y*qz + trans[1];
    float sz = b1z*qx + b2z*qy + b3z*qz + trans[2];
    src4[i] = make_float4(sx, sy, sz, sx*sx + sy*sy + sz*sz);

    float nx = sn[3*i], ny = sn[3*i+1], nz = sn[3*i+2];
    srcn4[i] = make_float4(b1x*nx + b2x*ny + b3x*nz,
                           b1y*nx + b2y*ny + b3y*nz,
                           b1z*nx + b2z*ny + b3z*nz, 0.f);
}

// ---------------------------------------------------------------------------
// Min kernel: block = 2048 A x 128 B(LDS). Inner loop tracks e = t2 - 2*dot
// (monotone per row; +s2 / clamp in epilogue). Chunk-local j is embedded in
// the low 8 mantissa bits of e (JCH=128 < 256), so min+argmin is a single
// v_and_or_b32 + v_min_f32: 5 VALU/pair total, no index registers.
// Quantization: <=2^-15 relative on e -> ~1e-4 on the loss (threshold 3e-3).
// Packed (d|idx) u64 atomicMin merges chunks (equal d -> smaller idx wins).
// Measured: ~8.0us = >=94% of the 5-op VALU-issue floor. 4-op variants
// (R6 rescan) and f32x2 packing (R4) both measured net-worse — do not retry.
// ---------------------------------------------------------------------------
__global__ __launch_bounds__(BT) void min_kernel(
    const float4* __restrict__ src4, const float4* __restrict__ tgt4,
    unsigned long long* __restrict__ min_s,
    unsigned long long* __restrict__ min_t, int N, int M)
{
    const float4* A; const float4* B; unsigned long long* outm; int nA, nB;
    if (blockIdx.z == 0) { A = src4; B = tgt4; outm = min_s; nA = N; nB = M; }
    else                 { A = tgt4; B = src4; outm = min_t; nA = M; nB = N; }

    const int tid   = threadIdx.x;
    const int aBase = blockIdx.x * (BT * MPT);
    const int jBase = blockIdx.y * JCH;
    if (aBase >= nA || jBase >= nB) return;   // block-uniform

    __shared__ float4 bs[JCH];

    float cx[MPT], cy[MPT], cz[MPT], s2[MPT], best[MPT];
    #pragma unroll
    for (int p = 0; p < MPT; p++) {
        int ia = aBase + p*BT + tid; if (ia >= nA) ia = 0;
        float4 a = A[ia];
        cx[p] = -2.f*a.x; cy[p] = -2.f*a.y; cz[p] = -2.f*a.z;
        s2[p] = a.w;
        best[p] = 3.4e38f;
    }
    if (tid < JCH) {
        int jb = jBase + tid;
        bs[tid] = B[jb < nB ? jb : nB - 1];
    }
    __syncthreads();

    int jLim = nB - jBase; if (jLim > JCH) jLim = JCH;
    #pragma unroll 2
    for (int j = 0; j < jLim; j++) {
        float4 b = bs[j];                    // wave-uniform -> LDS broadcast
        #pragma unroll
        for (int p = 0; p < MPT; p++) {
            float e = fmaf(cz[p], b.z, b.w);
            e = fmaf(cy[p], b.y, e);
            e = fmaf(cx[p], b.x, e);
            float em = __uint_as_float(
                (__float_as_uint(e) & 0xFFFFFF00u) | (unsigned int)j);
            best[p] = fminf(best[p], em);
        }
    }

    #pragma unroll
    for (int p = 0; p < MPT; p++) {
        int ia = aBase + p*BT + tid;
        if (ia < nA) {
            unsigned int eb = __float_as_uint(best[p]);
            int jloc = (int)(eb & 0xFFu);
            float ec = __uint_as_float(eb & 0xFFFFFF00u);
            float d = fmaxf(ec + s2[p], 0.f);
            unsigned long long pk =
                ((unsigned long long)__float_as_uint(d) << 32) |
                (unsigned int)(jBase + jloc);
            atomicMin(&outm[ia], pk);
        }
    }
}

// ---------------------------------------------------------------------------
// Reduce: per-element loss contribution -> block reduce -> atomicAdd
// ---------------------------------------------------------------------------
__global__ __launch_bounds__(BT) void reduce_kernel(
    const unsigned long long* __restrict__ min_s,
    const unsigned long long* __restrict__ min_t,
    const float4* __restrict__ srcn4, const float* __restrict__ tn,
    float* __restrict__ out, int N, int M)
{
    int gid = blockIdx.x * BT + threadIdx.x;
    float contrib = 0.f;

    if (gid < N) {
        unsigned long long pk = min_s[gid];
        float d = __uint_as_float((unsigned int)(pk >> 32));
        int idx = (int)(unsigned int)(pk & 0xffffffffull);
        float4 nv = srcn4[gid];
        float tx = tn[3*idx], ty = tn[3*idx+1], tz = tn[3*idx+2];
        float na = fmaxf(sqrtf(nv.x*nv.x + nv.y*nv.y + nv.z*nv.z), EPSV);
        float nb = fmaxf(sqrtf(tx*tx + ty*ty + tz*tz), EPSV);
        float cs = (nv.x*tx + nv.y*ty + nv.z*tz) / (na * nb);
        contrib = (FW * d + NW * (1.f - fabsf(cs))) * (1.f / N);
    } else if (gid < N + M) {
        int j = gid - N;
        unsigned long long pk = min_t[j];
        float d = __uint_as_float((unsigned int)(pk >> 32));
        int idx = (int)(unsigned int)(pk & 0xffffffffull);
        float tx = tn[3*j], ty = tn[3*j+1], tz = tn[3*j+2];
        float4 nv = srcn4[idx];
        float na = fmaxf(sqrtf(tx*tx + ty*ty + tz*tz), EPSV);
        float nb = fmaxf(sqrtf(nv.x*nv.x + nv.y*nv.y + nv.z*nv.z), EPSV);
        float cs = (tx*nv.x + ty*nv.y + tz*nv.z) / (na * nb);
        contrib = (BW * d + NW * (1.f - fabsf(cs))) * (1.f / M);
    }

    #pragma unroll
    for (int o = 32; o > 0; o >>= 1)
        contrib += __shfl_down(contrib, o, 64);

    __shared__ float wsum[BT/64];
    if ((threadIdx.x & 63) == 0) wsum[threadIdx.x >> 6] = contrib;
    __syncthreads();
    if (threadIdx.x == 0) {
        float s = 0.f;
        #pragma unroll
        for (int w = 0; w < BT/64; w++) s += wsum[w];
        atomicAdd(out, s);
    }
}

extern "C" void kernel_launch(void* const* d_in, const int* in_sizes, int n_in,
                              void* d_out, int out_size, void* d_ws, size_t ws_size,
                              hipStream_t stream) {
    const float* sp    = (const float*)d_in[0];
    const float* tp    = (const float*)d_in[1];
    const float* sn    = (const float*)d_in[2];
    const float* tn    = (const float*)d_in[3];
    const float* trans = (const float*)d_in[4];
    const float* r6    = (const float*)d_in[5];
    const float* scl   = (const float*)d_in[6];
    float* out = (float*)d_out;

    const int N = in_sizes[0] / 3;
    const int M = in_sizes[1] / 3;

    char* ws = (char*)d_ws;
    float4* src4  = (float4*)(ws);
    float4* tgt4  = (float4*)(ws + (size_t)16*N);
    float4* srcn4 = (float4*)(ws + (size_t)16*N + (size_t)16*M);
    unsigned long long* min_s =
        (unsigned long long*)(ws + (size_t)32*N + (size_t)16*M);
    unsigned long long* min_t = min_s + N;

    int nmax = N > M ? N : M;
    dim3 tgrid((nmax + BT - 1) / BT, 2);
    transform_kernel<<<tgrid, BT, 0, stream>>>(sp, tp, sn, trans, r6, scl,
                                               src4, tgt4, srcn4,
                                               min_s, min_t, out, N, M);

    dim3 mgrid((nmax + BT*MPT - 1) / (BT*MPT), (nmax + JCH - 1) / JCH, 2);
    min_kernel<<<mgrid, BT, 0, stream>>>(src4, tgt4, min_s, min_t, N, M);

    int rblocks = (N + M + BT - 1) / BT;
    reduce_kernel<<<rblocks, BT, 0, stream>>>(min_s, min_t, srcn4, tn, out, N, M);
}